// Round 5
// baseline (205.154 us; speedup 1.0000x reference)
//
#include <hip/hip_runtime.h>
#include <hip/hip_bf16.h>

#define FDIM 80
#define RDIM 20
#define RD1  21      // RDIM + 1 (deg folded in)
#define LDP  104     // LDS row stride (bf16)
#define WROW 96      // Wt row stride (bf16), K padded to 96
#define AROWS 16     // atoms per block in atom_mfma

typedef float  f32x4  __attribute__((ext_vector_type(4)));
typedef short  bf16x8 __attribute__((ext_vector_type(8)));

__device__ __forceinline__ float sp_f(float x){
  float e = __expf(-fabsf(x));
  return fmaxf(x, 0.f) + __logf(1.f + e);
}
__device__ __forceinline__ __hip_bfloat16 tob(float x){ return __float2bfloat16(x); }

// ---------------------------------------------------------------------------
// Weight prep: Wt[slot][j][k] = bf16(W[k][j]), zero-padded k in [80,96)
// ---------------------------------------------------------------------------
struct WPtrs { const float* p[21]; };

__global__ __launch_bounds__(256) void prep_weights(WPtrs wp, __hip_bfloat16* __restrict__ wt){
  const float* W = wp.p[blockIdx.x];
  __hip_bfloat16* dst = wt + (size_t)blockIdx.x * FDIM * WROW;
  for (int i = threadIdx.x; i < FDIM * WROW; i += 256){
    int j = i / WROW, k = i - j * WROW;
    dst[i] = __float2bfloat16(k < FDIM ? W[k * FDIM + j] : 0.f);
  }
}

// ---------------------------------------------------------------------------
// CSR build: hist -> scan -> reorder
// ---------------------------------------------------------------------------
__global__ __launch_bounds__(256) void hist_kernel(const int* __restrict__ idx12,
    int* __restrict__ cnt, int M){
  int g = blockIdx.x * 256 + threadIdx.x;
  if (g < M) atomicAdd(&cnt[idx12[g]], 1);
}

#define SCAN_T 1024
__global__ __launch_bounds__(SCAN_T) void scan_kernel(const int* __restrict__ cnt,
    int* __restrict__ rowstart, int* __restrict__ cursor, int N){
  __shared__ int part[SCAN_T];
  const int t = threadIdx.x;
  const int per = (N + SCAN_T - 1) / SCAN_T;
  const int b0 = t * per;
  int s = 0;
  for (int i = 0; i < per; i++){ int idx = b0 + i; if (idx < N) s += cnt[idx]; }
  part[t] = s; __syncthreads();
  for (int off = 1; off < SCAN_T; off <<= 1){
    int v = (t >= off) ? part[t - off] : 0;
    __syncthreads();
    part[t] += v;
    __syncthreads();
  }
  int ex = (t == 0) ? 0 : part[t - 1];
  for (int i = 0; i < per; i++){
    int idx = b0 + i;
    if (idx < N){ rowstart[idx] = ex; cursor[idx] = ex; ex += cnt[idx]; }
  }
}

__global__ __launch_bounds__(256) void reorder_kernel(const int* __restrict__ idx12,
    int* __restrict__ cursor, int* __restrict__ plist, int P){
  int g = blockIdx.x * 256 + threadIdx.x;
  if (g >= 2 * P) return;
  int a = idx12[g];
  int slot = atomicAdd(&cursor[a], 1);
  plist[slot] = (g < P) ? g : g - P;
}

// ---------------------------------------------------------------------------
// Gather: R2[n][r] = sum_{p in inc(n)} aev[p][r]; R2[n][20] = deg(n)
// 32 lanes per atom (r = lane, active r<=20), 8 atoms per 256-thread block.
// ---------------------------------------------------------------------------
__global__ __launch_bounds__(256) void gather_R2(const float* __restrict__ aev,
    const int* __restrict__ plist, const int* __restrict__ rowstart,
    const int* __restrict__ cnt, float* __restrict__ R2, int N)
{
  const int t = threadIdx.x;
  const int r = t & 31;
  const int n = blockIdx.x * 8 + (t >> 5);
  if (n >= N) return;
  const int st = rowstart[n];
  const int dg = cnt[n];
  if (r < RDIM){
    float acc = 0.f;
    int d = 0;
    for (; d + 4 <= dg; d += 4){
      int p0 = plist[st + d], p1 = plist[st + d + 1];
      int p2 = plist[st + d + 2], p3 = plist[st + d + 3];
      float v0 = aev[(size_t)p0 * RDIM + r];
      float v1 = aev[(size_t)p1 * RDIM + r];
      float v2 = aev[(size_t)p2 * RDIM + r];
      float v3 = aev[(size_t)p3 * RDIM + r];
      acc += (v0 + v1) + (v2 + v3);
    }
    for (; d < dg; d++){
      int p = plist[st + d];
      acc += aev[(size_t)p * RDIM + r];
    }
    R2[(size_t)n * RD1 + r] = acc;
  } else if (r == RDIM){
    R2[(size_t)n * RD1 + RDIM] = (float)dg;
  }
}

// ---------------------------------------------------------------------------
// S[n] = R2[n][0:20] @ Wg + R2[n][20]*bg
// ---------------------------------------------------------------------------
#define TPB2 320
__global__ __launch_bounds__(TPB2) void aevt_kernel(const float* __restrict__ R2,
    const float* __restrict__ Wg, const float* __restrict__ bg,
    float* __restrict__ S, int N)
{
  __shared__ float Rl[64][RD1];
  const int t = threadIdx.x;
  const int base = blockIdx.x * 64;
  for (int i = t; i < 64 * RD1; i += TPB2){
    int u = i / RD1, r = i - u * RD1;
    Rl[u][r] = R2[(size_t)(base + u) * RD1 + r];
  }
  const int j = t % FDIM, rg = t / FDIM;
  float wc[RDIM];
  #pragma unroll
  for (int r = 0; r < RDIM; r++) wc[r] = Wg[r * FDIM + j];
  float bgj = bg[j];
  __syncthreads();
  #pragma unroll 1
  for (int ui = 0; ui < 16; ui++){
    int u = rg + 4 * ui;
    float acc = Rl[u][RDIM] * bgj;
    #pragma unroll
    for (int r = 0; r < RDIM; r++) acc += Rl[u][r] * wc[r];
    S[(size_t)(base + u) * FDIM + j] = acc;
  }
}

// ---------------------------------------------------------------------------
// MFMA single-tile layer: wave nt owns output cols [16nt,16nt+16).
// A-frag: m=lane&15, k=(lane>>4)*8+e (+32ks). C/D: col=lane&15, row=(lane>>4)*4+i.
// ---------------------------------------------------------------------------
__device__ __forceinline__ f32x4 mfma_layer1(
    const __hip_bfloat16 (*in)[LDP], int arow, int kb, int j0, int nt,
    const __hip_bfloat16* __restrict__ wtm, const float* __restrict__ bias)
{
  const __hip_bfloat16* wp = &wtm[(size_t)(16*nt + j0) * WROW + kb];
  bf16x8 b0 = *(const bf16x8*)(const void*)(wp);
  bf16x8 b1 = *(const bf16x8*)(const void*)(wp + 32);
  bf16x8 b2 = *(const bf16x8*)(const void*)(wp + 64);
  const __hip_bfloat16* ap = &in[arow][kb];
  bf16x8 a0 = *(const bf16x8*)(const void*)(ap);
  bf16x8 a1 = *(const bf16x8*)(const void*)(ap + 32);
  bf16x8 a2 = *(const bf16x8*)(const void*)(ap + 64);
  float b = bias[16*nt + j0];
  f32x4 acc = (f32x4){b, b, b, b};
  acc = __builtin_amdgcn_mfma_f32_16x16x32_bf16(a0, b0, acc, 0, 0, 0);
  acc = __builtin_amdgcn_mfma_f32_16x16x32_bf16(a1, b1, acc, 0, 0, 0);
  acc = __builtin_amdgcn_mfma_f32_16x16x32_bf16(a2, b2, acc, 0, 0, 0);
  return acc;
}

__device__ __forceinline__ void res1(f32x4& cur,
    __hip_bfloat16 (*bA)[LDP], __hip_bfloat16 (*bB)[LDP],
    int arow, int kb, int j0, int r0, int nt,
    const __hip_bfloat16* __restrict__ w1, const float* __restrict__ b1,
    const __hip_bfloat16* __restrict__ w2, const float* __restrict__ b2)
{
  f32x4 acc = mfma_layer1(bA, arow, kb, j0, nt, w1, b1);
  int col = 16*nt + j0;
  #pragma unroll
  for (int i = 0; i < 4; i++) bB[r0 + i][col] = tob(sp_f(acc[i]));
  __syncthreads();
  acc = mfma_layer1(bB, arow, kb, j0, nt, w2, b2);
  #pragma unroll
  for (int i = 0; i < 4; i++){
    cur[i] = sp_f(acc[i] + cur[i]);
    bA[r0 + i][col] = tob(cur[i]);
  }
  __syncthreads();
}

// ---------------------------------------------------------------------------
// Atom kernel: 16 atoms/block, 5 symmetric waves (one 16-col block each)
// ---------------------------------------------------------------------------
__global__ __launch_bounds__(320) void atom_mfma(
    const int*   __restrict__ species,
    const float* __restrict__ features,
    const float* __restrict__ S,
    const __hip_bfloat16* __restrict__ wt,
    const float* __restrict__ bJ, const float* __restrict__ bI,
    const float* __restrict__ ib1, const float* __restrict__ ib2,
    const float* __restrict__ gate, const float* __restrict__ bint,
    const float* __restrict__ ab1, const float* __restrict__ ab2,
    const float* __restrict__ ob1, const float* __restrict__ ob2,
    const float* __restrict__ Wout, const float* __restrict__ bout,
    float* __restrict__ out_e, float* __restrict__ out_f)
{
  __shared__ __align__(16) __hip_bfloat16 bufA[AROWS][LDP];
  __shared__ __align__(16) __hip_bfloat16 bufB[AROWS][LDP];
  __shared__ __align__(16) __hip_bfloat16 xfb[AROWS][LDP];
  __shared__ float mskl[AROWS];
  __shared__ float evp[5][AROWS];

  const int t    = threadIdx.x;
  const int lane = t & 63;
  const int nt   = t >> 6;          // 0..4 : output column block
  const int base = blockIdx.x * AROWS;

  // stage features: raw bf16 -> xfb, softplus bf16 -> bufA
  for (int i = t; i < AROWS * FDIM; i += 320){
    int row = i / FDIM, col = i - row * FDIM;
    float v = features[(size_t)(base + row) * FDIM + col];
    xfb [row][col] = tob(v);
    bufA[row][col] = tob(sp_f(v));
  }
  // zero K-pad cols [80,96) in all three tiles
  for (int i = t; i < 3 * AROWS * 16; i += 320){
    int b = i / (AROWS * 16), rem = i % (AROWS * 16);
    int row = rem >> 4, col = FDIM + (rem & 15);
    if      (b == 0) bufA[row][col] = tob(0.f);
    else if (b == 1) bufB[row][col] = tob(0.f);
    else             xfb [row][col] = tob(0.f);
  }
  if (t < AROWS) mskl[t] = (species[base + t] != -1) ? 1.f : 0.f;
  __syncthreads();

  const int j0   = lane & 15;
  const int g    = lane >> 4;
  const int kb   = g * 8;
  const int arow = j0;
  const int r0   = g * 4;
  const int col  = 16*nt + j0;

  f32x4 cur;

  // proto = sp(sp(f)@WJ+bJ) * S + (f@WI+bI)*mask
  {
    f32x4 accJ = mfma_layer1(bufA, arow, kb, j0, nt, wt + (size_t)0*FDIM*WROW, bJ);
    f32x4 accI = mfma_layer1(xfb , arow, kb, j0, nt, wt + (size_t)1*FDIM*WROW, bI);
    __syncthreads();   // bufA reads done before overwrite
    #pragma unroll
    for (int i = 0; i < 4; i++){
      float Sv = S[(size_t)(base + r0 + i) * FDIM + col];
      float m  = mskl[r0 + i];
      cur[i] = sp_f(accJ[i]) * Sv + accI[i] * m;
      bufA[r0 + i][col] = tob(cur[i]);
    }
  }
  __syncthreads();

  // message = res_stack(proto, iW)
  #pragma unroll 1
  for (int ir = 0; ir < 3; ir++)
    res1(cur, bufA, bufB, arow, kb, j0, r0, nt,
         wt + (size_t)(3+2*ir)*FDIM*WROW, ib1 + ir*FDIM,
         wt + (size_t)(4+2*ir)*FDIM*WROW, ib2 + ir*FDIM);

  // nd = f*gate + sp(message)@Wint + bint
  {
    #pragma unroll
    for (int i = 0; i < 4; i++) bufB[r0 + i][col] = tob(sp_f(cur[i]));
    __syncthreads();
    f32x4 acc = mfma_layer1(bufB, arow, kb, j0, nt, wt + (size_t)2*FDIM*WROW, bint);
    float gj = gate[col];
    #pragma unroll
    for (int i = 0; i < 4; i++){
      float xv = __bfloat162float(xfb[r0 + i][col]);
      cur[i] = xv * gj + acc[i];
      bufA[r0 + i][col] = tob(cur[i]);
    }
    __syncthreads();
  }

  // nd = res_stack(nd, aW)
  #pragma unroll 1
  for (int ir = 0; ir < 3; ir++)
    res1(cur, bufA, bufB, arow, kb, j0, r0, nt,
         wt + (size_t)(9+2*ir)*FDIM*WROW, ab1 + ir*FDIM,
         wt + (size_t)(10+2*ir)*FDIM*WROW, ab2 + ir*FDIM);

  // out_features = nd * mask
  #pragma unroll
  for (int i = 0; i < 4; i++)
    out_f[(size_t)(base + r0 + i) * FDIM + col] = cur[i] * mskl[r0 + i];

  // t3 = res_stack(nd, oW)
  #pragma unroll 1
  for (int ir = 0; ir < 3; ir++)
    res1(cur, bufA, bufB, arow, kb, j0, r0, nt,
         wt + (size_t)(15+2*ir)*FDIM*WROW, ob1 + ir*FDIM,
         wt + (size_t)(16+2*ir)*FDIM*WROW, ob2 + ir*FDIM);

  // energies = (sp(t3) @ Wout + bout) * mask
  {
    float wv = Wout[col];
    float ev[4];
    #pragma unroll
    for (int i = 0; i < 4; i++) ev[i] = sp_f(cur[i]) * wv;
    #pragma unroll
    for (int off = 1; off < 16; off <<= 1){
      #pragma unroll
      for (int i = 0; i < 4; i++) ev[i] += __shfl_xor(ev[i], off);
    }
    if (j0 == 0){
      #pragma unroll
      for (int i = 0; i < 4; i++) evp[nt][r0 + i] = ev[i];
    }
  }
  __syncthreads();
  if (t < AROWS)
    out_e[base + t] = (evp[0][t] + evp[1][t] + evp[2][t] + evp[3][t] + evp[4][t]
                       + bout[0]) * mskl[t];
}

// ---------------------------------------------------------------------------
extern "C" void kernel_launch(void* const* d_in, const int* in_sizes, int n_in,
                              void* d_out, int out_size, void* d_ws, size_t ws_size,
                              hipStream_t stream) {
  const int*   species  = (const int*)  d_in[0];
  const float* features = (const float*)d_in[1];
  const float* aev      = (const float*)d_in[2];
  const int*   idx12    = (const int*)  d_in[3];
  const float* WI   = (const float*)d_in[4];  const float* bI   = (const float*)d_in[5];
  const float* Wg   = (const float*)d_in[6];  const float* bg   = (const float*)d_in[7];
  const float* WJ   = (const float*)d_in[8];  const float* bJ   = (const float*)d_in[9];
  const float* iW1  = (const float*)d_in[10]; const float* ib1  = (const float*)d_in[11];
  const float* iW2  = (const float*)d_in[12]; const float* ib2  = (const float*)d_in[13];
  const float* gate = (const float*)d_in[14];
  const float* Wint = (const float*)d_in[15]; const float* bint = (const float*)d_in[16];
  const float* aW1  = (const float*)d_in[17]; const float* ab1  = (const float*)d_in[18];
  const float* aW2  = (const float*)d_in[19]; const float* ab2  = (const float*)d_in[20];
  const float* oW1  = (const float*)d_in[21]; const float* ob1  = (const float*)d_in[22];
  const float* oW2  = (const float*)d_in[23]; const float* ob2  = (const float*)d_in[24];
  const float* Wout = (const float*)d_in[25]; const float* bout = (const float*)d_in[26];

  const int N = in_sizes[1] / FDIM;   // 16384
  const int P = in_sizes[2] / RDIM;   // 393216

  float* R2 = (float*)d_ws;                                      // N*21 f
  float* S  = R2 + (size_t)N * RD1;                              // N*80 f
  __hip_bfloat16* wt = (__hip_bfloat16*)(S + (size_t)N * FDIM);  // 21*80*96 bf16
  int* cnt      = (int*)(wt + (size_t)21 * FDIM * WROW);         // N
  int* rowstart = cnt + N;                                       // N
  int* cursor   = rowstart + N;                                  // N
  int* plist    = cursor + N;                                    // 2P

  float* out_e = (float*)d_out;
  float* out_f = out_e + N;

  hipMemsetAsync(cnt, 0, (size_t)N * sizeof(int), stream);

  WPtrs wp;
  wp.p[0] = WJ; wp.p[1] = WI; wp.p[2] = Wint;
  for (int ir = 0; ir < 3; ir++){
    wp.p[3  + 2*ir] = iW1 + ir*FDIM*FDIM; wp.p[4  + 2*ir] = iW2 + ir*FDIM*FDIM;
    wp.p[9  + 2*ir] = aW1 + ir*FDIM*FDIM; wp.p[10 + 2*ir] = aW2 + ir*FDIM*FDIM;
    wp.p[15 + 2*ir] = oW1 + ir*FDIM*FDIM; wp.p[16 + 2*ir] = oW2 + ir*FDIM*FDIM;
  }
  prep_weights<<<21, 256, 0, stream>>>(wp, wt);

  hist_kernel<<<(2*P + 255) / 256, 256, 0, stream>>>(idx12, cnt, 2*P);
  scan_kernel<<<1, SCAN_T, 0, stream>>>(cnt, rowstart, cursor, N);
  reorder_kernel<<<(2*P + 255) / 256, 256, 0, stream>>>(idx12, cursor, plist, P);
  gather_R2<<<(N + 7) / 8, 256, 0, stream>>>(aev, plist, rowstart, cnt, R2, N);
  aevt_kernel<<<(N + 63) / 64, TPB2, 0, stream>>>(R2, Wg, bg, S, N);

  atom_mfma<<<(N + AROWS - 1) / AROWS, 320, 0, stream>>>(species, features, S, wt,
      bJ, bI, ib1, ib2, gate, bint, ab1, ab2, ob1, ob2, Wout, bout, out_e, out_f);
}

// Round 6
// 156.040 us; speedup vs baseline: 1.3148x; 1.3148x over previous
//
#include <hip/hip_runtime.h>
#include <hip/hip_bf16.h>

#define FDIM 80
#define RDIM 20
#define RD1  21      // RDIM + 1 (deg folded in)
#define NSLOT 11     // u64 slots per atom row (10 aev pairs + deg)
#define LDP  104     // LDS row stride (bf16)
#define WROW 96      // Wt row stride (bf16), K padded to 96

#define FIX_SCALE 2097152.0f        // 2^21
#define FIX_INV   4.76837158203125e-7f  // 2^-21

typedef float  f32x4  __attribute__((ext_vector_type(4)));
typedef short  bf16x8 __attribute__((ext_vector_type(8)));

__device__ __forceinline__ float sp_f(float x){
  float e = __expf(-fabsf(x));
  return fmaxf(x, 0.f) + __logf(1.f + e);
}
__device__ __forceinline__ __hip_bfloat16 tob(float x){ return __float2bfloat16(x); }

// ---------------------------------------------------------------------------
// Weight prep: Wt[slot][j][k] = bf16(W[k][j]), zero-padded k in [80,96)
// ---------------------------------------------------------------------------
struct WPtrs { const float* p[21]; };

__global__ __launch_bounds__(256) void prep_weights(WPtrs wp, __hip_bfloat16* __restrict__ wt){
  const float* W = wp.p[blockIdx.x];
  __hip_bfloat16* dst = wt + (size_t)blockIdx.x * FDIM * WROW;
  for (int i = threadIdx.x; i < FDIM * WROW; i += 256){
    int j = i / WROW, k = i - j * WROW;
    dst[i] = __float2bfloat16(k < FDIM ? W[k * FDIM + j] : 0.f);
  }
}

// ---------------------------------------------------------------------------
// Scatter, u64 fixed-point: R2u[n][s] += pack(aev[p][2s], aev[p][2s+1])
// slot 10 low field accumulates deg (scaled). Values nonneg, no carry.
// ---------------------------------------------------------------------------
__global__ __launch_bounds__(256) void scatter_u64(const float2* __restrict__ aev2,
    const int* __restrict__ idx12, unsigned long long* __restrict__ R2u, int P)
{
  int g = blockIdx.x * 256 + threadIdx.x;
  if (g >= P * NSLOT) return;
  int p = g / NSLOT, s = g - p * NSLOT;
  unsigned long long v;
  if (s < 10){
    float2 a = aev2[(size_t)p * 10 + s];
    unsigned long long lo = (unsigned long long)__float2uint_rn(a.x * FIX_SCALE);
    unsigned long long hi = (unsigned long long)__float2uint_rn(a.y * FIX_SCALE);
    v = lo | (hi << 32);
  } else {
    v = (unsigned long long)(1u << 21);   // deg increment
  }
  int i1 = idx12[p], i2 = idx12[P + p];
  atomicAdd(&R2u[(size_t)i1 * NSLOT + s], v);
  atomicAdd(&R2u[(size_t)i2 * NSLOT + s], v);
}

// ---------------------------------------------------------------------------
// S[n] = R2[n][0:20] @ Wg + deg(n)*bg      (unpacks fixed-point u64)
// ---------------------------------------------------------------------------
#define TPB2 320
__global__ __launch_bounds__(TPB2) void aevt_kernel(
    const unsigned long long* __restrict__ R2u,
    const float* __restrict__ Wg, const float* __restrict__ bg,
    float* __restrict__ S, int N)
{
  __shared__ float Rl[64][2 * NSLOT + 1];
  const int t = threadIdx.x;
  const int base = blockIdx.x * 64;
  for (int i = t; i < 64 * NSLOT; i += TPB2){
    int u = i / NSLOT, s = i - u * NSLOT;
    unsigned long long v = R2u[(size_t)(base + u) * NSLOT + s];
    Rl[u][2*s]     = (float)(unsigned int)(v & 0xffffffffULL) * FIX_INV;
    Rl[u][2*s + 1] = (float)(unsigned int)(v >> 32) * FIX_INV;
  }
  const int j = t % FDIM, rg = t / FDIM;
  float wc[RDIM];
  #pragma unroll
  for (int r = 0; r < RDIM; r++) wc[r] = Wg[r * FDIM + j];
  float bgj = bg[j];
  __syncthreads();
  #pragma unroll 1
  for (int ui = 0; ui < 16; ui++){
    int u = rg + 4 * ui;
    float acc = Rl[u][RDIM] * bgj;       // Rl[u][20] = deg
    #pragma unroll
    for (int r = 0; r < RDIM; r++) acc += Rl[u][r] * wc[r];
    S[(size_t)(base + u) * FDIM + j] = acc;
  }
}

// ---------------------------------------------------------------------------
// MFMA layer: batch-load B-frags to regs, then MFMA chain.
// A-frag: m=lane&15, k=(lane>>4)*8+e (+32ks). C/D: col=lane&15+16nt,
// row=(lane>>4)*4+i.  nt range [ntbase, ntbase+nnt), nnt in {2,3}.
// ---------------------------------------------------------------------------
__device__ __forceinline__ void mfma_layer(f32x4 acc[3],
    const __hip_bfloat16 (*in)[LDP], int arow, int kb, int j0,
    int ntbase, int nnt,
    const __hip_bfloat16* __restrict__ wtm, const float* __restrict__ bias)
{
  bf16x8 bfr[3][3];
  #pragma unroll
  for (int q = 0; q < 3; q++) if (q < nnt){
    #pragma unroll
    for (int ks = 0; ks < 3; ks++)
      bfr[q][ks] = *(const bf16x8*)(const void*)
          &wtm[(size_t)(16*(ntbase+q) + j0) * WROW + kb + ks*32];
  }
  bf16x8 a[3];
  #pragma unroll
  for (int ks = 0; ks < 3; ks++)
    a[ks] = *(const bf16x8*)(const void*)&in[arow][kb + ks*32];
  #pragma unroll
  for (int q = 0; q < 3; q++) if (q < nnt){
    float b = bias[16*(ntbase+q) + j0];
    acc[q] = (f32x4){b, b, b, b};
  }
  #pragma unroll
  for (int ks = 0; ks < 3; ks++){
    #pragma unroll
    for (int q = 0; q < 3; q++) if (q < nnt)
      acc[q] = __builtin_amdgcn_mfma_f32_16x16x32_bf16(a[ks], bfr[q][ks], acc[q], 0, 0, 0);
  }
}

__device__ __forceinline__ void res_mfma(f32x4 cur[3],
    __hip_bfloat16 (*bA)[LDP], __hip_bfloat16 (*bB)[LDP],
    int arow, int kb, int j0, int r0, int ntbase, int nnt,
    const __hip_bfloat16* __restrict__ w1, const float* __restrict__ b1,
    const __hip_bfloat16* __restrict__ w2, const float* __restrict__ b2)
{
  f32x4 acc[3];
  mfma_layer(acc, bA, arow, kb, j0, ntbase, nnt, w1, b1);
  #pragma unroll
  for (int q = 0; q < 3; q++) if (q < nnt){
    int col = 16*(ntbase+q) + j0;
    #pragma unroll
    for (int i = 0; i < 4; i++) bB[r0 + i][col] = tob(sp_f(acc[q][i]));
  }
  __syncthreads();
  mfma_layer(acc, bB, arow, kb, j0, ntbase, nnt, w2, b2);
  #pragma unroll
  for (int q = 0; q < 3; q++) if (q < nnt){
    int col = 16*(ntbase+q) + j0;
    #pragma unroll
    for (int i = 0; i < 4; i++){
      cur[q][i] = sp_f(acc[q][i] + cur[q][i]);
      bA[r0 + i][col] = tob(cur[q][i]);
    }
  }
  __syncthreads();
}

// ---------------------------------------------------------------------------
// Atom kernel: 64 atoms/block, 8 waves = 4 row-strips x 2 col-groups
// ---------------------------------------------------------------------------
__global__ __launch_bounds__(512) void atom_mfma(
    const int*   __restrict__ species,
    const float* __restrict__ features,
    const float* __restrict__ S,
    const __hip_bfloat16* __restrict__ wt,
    const float* __restrict__ bJ, const float* __restrict__ bI,
    const float* __restrict__ ib1, const float* __restrict__ ib2,
    const float* __restrict__ gate, const float* __restrict__ bint,
    const float* __restrict__ ab1, const float* __restrict__ ab2,
    const float* __restrict__ ob1, const float* __restrict__ ob2,
    const float* __restrict__ Wout, const float* __restrict__ bout,
    float* __restrict__ out_e, float* __restrict__ out_f)
{
  __shared__ __align__(16) __hip_bfloat16 bufA[64][LDP];
  __shared__ __align__(16) __hip_bfloat16 bufB[64][LDP];
  __shared__ __align__(16) __hip_bfloat16 xfb[64][LDP];
  __shared__ float mskl[64];
  __shared__ float evp[2][64];

  const int t     = threadIdx.x;
  const int lane  = t & 63;
  const int w     = t >> 6;        // 0..7
  const int strip = w & 3;         // row strip
  const int cg    = w >> 2;        // column group
  const int wrow0 = strip * 16;
  const int base  = blockIdx.x * 64;

  const int ntbase = cg ? 3 : 0;
  const int nnt    = cg ? 2 : 3;

  // stage features: raw bf16 -> xfb, softplus bf16 -> bufA  (coalesced)
  for (int i = t; i < 64 * FDIM; i += 512){
    int row = i / FDIM, col = i - row * FDIM;
    float v = features[(size_t)(base + row) * FDIM + col];
    xfb [row][col] = tob(v);
    bufA[row][col] = tob(sp_f(v));
  }
  // zero K-pad cols [80,96) in all three tiles
  for (int i = t; i < 3 * 64 * 16; i += 512){
    int b = i >> 10, rem = i & 1023;
    int row = rem >> 4, col = FDIM + (rem & 15);
    if      (b == 0) bufA[row][col] = tob(0.f);
    else if (b == 1) bufB[row][col] = tob(0.f);
    else             xfb [row][col] = tob(0.f);
  }
  if (t < 64) mskl[t] = (species[base + t] != -1) ? 1.f : 0.f;
  __syncthreads();

  const int j0   = lane & 15;
  const int g    = lane >> 4;
  const int kb   = g * 8;
  const int arow = wrow0 + j0;
  const int r0   = wrow0 + g * 4;

  f32x4 cur[3];

  // proto = sp(sp(f)@WJ+bJ) * S + (f@WI+bI)*mask
  {
    f32x4 accJ[3], accI[3];
    mfma_layer(accJ, bufA, arow, kb, j0, ntbase, nnt, wt + (size_t)0*FDIM*WROW, bJ);
    mfma_layer(accI, xfb , arow, kb, j0, ntbase, nnt, wt + (size_t)1*FDIM*WROW, bI);
    __syncthreads();   // bufA reads done before overwrite
    #pragma unroll
    for (int q = 0; q < 3; q++) if (q < nnt){
      int col = 16*(ntbase+q) + j0;
      #pragma unroll
      for (int i = 0; i < 4; i++){
        float Sv = S[(size_t)(base + r0 + i) * FDIM + col];
        float m  = mskl[r0 + i];
        cur[q][i] = sp_f(accJ[q][i]) * Sv + accI[q][i] * m;
        bufA[r0 + i][col] = tob(cur[q][i]);
      }
    }
  }
  __syncthreads();

  // message = res_stack(proto, iW)
  #pragma unroll 1
  for (int ir = 0; ir < 3; ir++)
    res_mfma(cur, bufA, bufB, arow, kb, j0, r0, ntbase, nnt,
             wt + (size_t)(3+2*ir)*FDIM*WROW, ib1 + ir*FDIM,
             wt + (size_t)(4+2*ir)*FDIM*WROW, ib2 + ir*FDIM);

  // nd = f*gate + sp(message)@Wint + bint
  {
    #pragma unroll
    for (int q = 0; q < 3; q++) if (q < nnt){
      int col = 16*(ntbase+q) + j0;
      #pragma unroll
      for (int i = 0; i < 4; i++) bufB[r0 + i][col] = tob(sp_f(cur[q][i]));
    }
    __syncthreads();
    f32x4 acc[3];
    mfma_layer(acc, bufB, arow, kb, j0, ntbase, nnt, wt + (size_t)2*FDIM*WROW, bint);
    #pragma unroll
    for (int q = 0; q < 3; q++) if (q < nnt){
      int col = 16*(ntbase+q) + j0;
      float gj = gate[col];
      #pragma unroll
      for (int i = 0; i < 4; i++){
        float xv = __bfloat162float(xfb[r0 + i][col]);
        cur[q][i] = xv * gj + acc[q][i];
        bufA[r0 + i][col] = tob(cur[q][i]);
      }
    }
    __syncthreads();
  }

  // nd = res_stack(nd, aW)
  #pragma unroll 1
  for (int ir = 0; ir < 3; ir++)
    res_mfma(cur, bufA, bufB, arow, kb, j0, r0, ntbase, nnt,
             wt + (size_t)(9+2*ir)*FDIM*WROW, ab1 + ir*FDIM,
             wt + (size_t)(10+2*ir)*FDIM*WROW, ab2 + ir*FDIM);

  // out_features = nd * mask
  #pragma unroll
  for (int q = 0; q < 3; q++) if (q < nnt){
    int col = 16*(ntbase+q) + j0;
    #pragma unroll
    for (int i = 0; i < 4; i++)
      out_f[(size_t)(base + r0 + i) * FDIM + col] = cur[q][i] * mskl[r0 + i];
  }

  // t3 = res_stack(nd, oW)
  #pragma unroll 1
  for (int ir = 0; ir < 3; ir++)
    res_mfma(cur, bufA, bufB, arow, kb, j0, r0, ntbase, nnt,
             wt + (size_t)(15+2*ir)*FDIM*WROW, ob1 + ir*FDIM,
             wt + (size_t)(16+2*ir)*FDIM*WROW, ob2 + ir*FDIM);

  // energies = (sp(t3) @ Wout + bout) * mask   (reduce over j0, then cg)
  {
    float ev[4] = {0.f, 0.f, 0.f, 0.f};
    #pragma unroll
    for (int q = 0; q < 3; q++) if (q < nnt){
      float wv = Wout[16*(ntbase+q) + j0];
      #pragma unroll
      for (int i = 0; i < 4; i++) ev[i] += sp_f(cur[q][i]) * wv;
    }
    #pragma unroll
    for (int off = 1; off < 16; off <<= 1){
      #pragma unroll
      for (int i = 0; i < 4; i++) ev[i] += __shfl_xor(ev[i], off);
    }
    if (j0 == 0){
      #pragma unroll
      for (int i = 0; i < 4; i++) evp[cg][r0 + i] = ev[i];
    }
  }
  __syncthreads();
  if (t < 64)
    out_e[base + t] = (evp[0][t] + evp[1][t] + bout[0]) * mskl[t];
}

// ---------------------------------------------------------------------------
extern "C" void kernel_launch(void* const* d_in, const int* in_sizes, int n_in,
                              void* d_out, int out_size, void* d_ws, size_t ws_size,
                              hipStream_t stream) {
  const int*   species  = (const int*)  d_in[0];
  const float* features = (const float*)d_in[1];
  const float* aev      = (const float*)d_in[2];
  const int*   idx12    = (const int*)  d_in[3];
  const float* WI   = (const float*)d_in[4];  const float* bI   = (const float*)d_in[5];
  const float* Wg   = (const float*)d_in[6];  const float* bg   = (const float*)d_in[7];
  const float* WJ   = (const float*)d_in[8];  const float* bJ   = (const float*)d_in[9];
  const float* iW1  = (const float*)d_in[10]; const float* ib1  = (const float*)d_in[11];
  const float* iW2  = (const float*)d_in[12]; const float* ib2  = (const float*)d_in[13];
  const float* gate = (const float*)d_in[14];
  const float* Wint = (const float*)d_in[15]; const float* bint = (const float*)d_in[16];
  const float* aW1  = (const float*)d_in[17]; const float* ab1  = (const float*)d_in[18];
  const float* aW2  = (const float*)d_in[19]; const float* ab2  = (const float*)d_in[20];
  const float* oW1  = (const float*)d_in[21]; const float* ob1  = (const float*)d_in[22];
  const float* oW2  = (const float*)d_in[23]; const float* ob2  = (const float*)d_in[24];
  const float* Wout = (const float*)d_in[25]; const float* bout = (const float*)d_in[26];

  const int N = in_sizes[1] / FDIM;   // 16384
  const int P = in_sizes[2] / RDIM;   // 393216

  unsigned long long* R2u = (unsigned long long*)d_ws;           // N*11 u64
  float* S = (float*)(R2u + (size_t)N * NSLOT);                  // N*80 f32
  __hip_bfloat16* wt = (__hip_bfloat16*)(S + (size_t)N * FDIM);  // 21*80*96 bf16

  float* out_e = (float*)d_out;
  float* out_f = out_e + N;

  hipMemsetAsync(R2u, 0, (size_t)N * NSLOT * sizeof(unsigned long long), stream);

  WPtrs wp;
  wp.p[0] = WJ; wp.p[1] = WI; wp.p[2] = Wint;
  for (int ir = 0; ir < 3; ir++){
    wp.p[3  + 2*ir] = iW1 + ir*FDIM*FDIM; wp.p[4  + 2*ir] = iW2 + ir*FDIM*FDIM;
    wp.p[9  + 2*ir] = aW1 + ir*FDIM*FDIM; wp.p[10 + 2*ir] = aW2 + ir*FDIM*FDIM;
    wp.p[15 + 2*ir] = oW1 + ir*FDIM*FDIM; wp.p[16 + 2*ir] = oW2 + ir*FDIM*FDIM;
  }
  prep_weights<<<21, 256, 0, stream>>>(wp, wt);

  scatter_u64<<<((size_t)P * NSLOT + 255) / 256, 256, 0, stream>>>(
      (const float2*)aev, idx12, R2u, P);
  aevt_kernel<<<(N + 63) / 64, TPB2, 0, stream>>>(R2u, Wg, bg, S, N);

  atom_mfma<<<(N + 63) / 64, 512, 0, stream>>>(species, features, S, wt,
      bJ, bI, ib1, ib2, gate, bint, ab1, ab2, ob1, ob2, Wout, bout, out_e, out_f);
}

// Round 7
// 114.539 us; speedup vs baseline: 1.7911x; 1.3623x over previous
//
#include <hip/hip_runtime.h>
#include <hip/hip_bf16.h>

#define FDIM 80
#define RDIM 20
#define NSLOT 6      // u64 slots per atom row: 24 x 16-bit fields (20 aev + deg + 3 pad)
#define LDP  104     // LDS row stride (bf16)
#define WROW 96      // Wt row stride (bf16), K padded to 96
#define AROWS 32     // atoms per block in atom_mfma

#define FIX_SCALE 512.0f        // 2^9
#define FIX_INV   0.001953125f  // 2^-9

typedef float  f32x4  __attribute__((ext_vector_type(4)));
typedef short  bf16x8 __attribute__((ext_vector_type(8)));

__device__ __forceinline__ float sp_f(float x){
  float e = __expf(-fabsf(x));
  return fmaxf(x, 0.f) + __logf(1.f + e);
}
__device__ __forceinline__ __hip_bfloat16 tob(float x){ return __float2bfloat16(x); }

// ---------------------------------------------------------------------------
// Weight prep: Wt[slot][j][k] = bf16(W[k][j]), zero-padded k in [80,96)
// ---------------------------------------------------------------------------
struct WPtrs { const float* p[21]; };

__global__ __launch_bounds__(256) void prep_weights(WPtrs wp, __hip_bfloat16* __restrict__ wt){
  const float* W = wp.p[blockIdx.x];
  __hip_bfloat16* dst = wt + (size_t)blockIdx.x * FDIM * WROW;
  for (int i = threadIdx.x; i < FDIM * WROW; i += 256){
    int j = i / WROW, k = i - j * WROW;
    dst[i] = __float2bfloat16(k < FDIM ? W[k * FDIM + j] : 0.f);
  }
}

// ---------------------------------------------------------------------------
// Scatter, 16-bit fixed-point, 4 fields per u64:
//   slot s<5 : fields = round(aev[p][4s..4s+3] * 512)
//   slot 5   : field0 = 512 (deg increment)
// Values nonneg; max field sum deg_max*512 < 2^16 -> no cross-field carry.
// ---------------------------------------------------------------------------
__global__ __launch_bounds__(256) void scatter_p16(const float* __restrict__ aev,
    const int* __restrict__ idx12, unsigned long long* __restrict__ R6u, int P)
{
  int g = blockIdx.x * 256 + threadIdx.x;
  if (g >= P * NSLOT) return;
  int p = g / NSLOT, s = g - p * NSLOT;
  unsigned long long v;
  if (s < 5){
    float4 a = ((const float4*)(aev + (size_t)p * RDIM))[s];
    unsigned long long f0 = (unsigned long long)__float2uint_rn(a.x * FIX_SCALE);
    unsigned long long f1 = (unsigned long long)__float2uint_rn(a.y * FIX_SCALE);
    unsigned long long f2 = (unsigned long long)__float2uint_rn(a.z * FIX_SCALE);
    unsigned long long f3 = (unsigned long long)__float2uint_rn(a.w * FIX_SCALE);
    v = f0 | (f1 << 16) | (f2 << 32) | (f3 << 48);
  } else {
    v = 512ULL;   // deg increment (unpacks to 1.0)
  }
  int i1 = idx12[p], i2 = idx12[P + p];
  atomicAdd(&R6u[(size_t)i1 * NSLOT + s], v);
  atomicAdd(&R6u[(size_t)i2 * NSLOT + s], v);
}

// ---------------------------------------------------------------------------
// S[n] = R[n][0:20] @ Wg + deg(n)*bg      (unpacks 16-bit fixed-point)
// ---------------------------------------------------------------------------
#define TPB2 320
__global__ __launch_bounds__(TPB2) void aevt_kernel(
    const unsigned long long* __restrict__ R6u,
    const float* __restrict__ Wg, const float* __restrict__ bg,
    float* __restrict__ S, int N)
{
  __shared__ float Rl[64][4 * NSLOT];
  const int t = threadIdx.x;
  const int base = blockIdx.x * 64;
  for (int i = t; i < 64 * NSLOT; i += TPB2){
    int u = i / NSLOT, s = i - u * NSLOT;
    unsigned long long v = R6u[(size_t)(base + u) * NSLOT + s];
    #pragma unroll
    for (int f = 0; f < 4; f++)
      Rl[u][4*s + f] = (float)((unsigned int)(v >> (16*f)) & 0xffffu) * FIX_INV;
  }
  const int j = t % FDIM, rg = t / FDIM;
  float wc[RDIM];
  #pragma unroll
  for (int r = 0; r < RDIM; r++) wc[r] = Wg[r * FDIM + j];
  float bgj = bg[j];
  __syncthreads();
  #pragma unroll 1
  for (int ui = 0; ui < 16; ui++){
    int u = rg + 4 * ui;
    float acc = Rl[u][RDIM] * bgj;       // Rl[u][20] = deg
    #pragma unroll
    for (int r = 0; r < RDIM; r++) acc += Rl[u][r] * wc[r];
    S[(size_t)(base + u) * FDIM + j] = acc;
  }
}

// ---------------------------------------------------------------------------
// MFMA layer over 2 row-strips; B-frags loaded once, reused across strips.
// A-frag: m=lane&15, k=(lane>>4)*8+e (+32ks). C/D: col=lane&15, row=(lane>>4)*4+i.
// ---------------------------------------------------------------------------
__device__ __forceinline__ void mfma_layer2(f32x4 acc[2],
    const __hip_bfloat16 (*in)[LDP], int j0, int kb, int nt,
    const __hip_bfloat16* __restrict__ wtm, const float* __restrict__ bias)
{
  const __hip_bfloat16* wp = &wtm[(size_t)(16*nt + j0) * WROW + kb];
  bf16x8 b0 = *(const bf16x8*)(const void*)(wp);
  bf16x8 b1 = *(const bf16x8*)(const void*)(wp + 32);
  bf16x8 b2 = *(const bf16x8*)(const void*)(wp + 64);
  float bv = bias[16*nt + j0];
  #pragma unroll
  for (int s = 0; s < 2; s++){
    const __hip_bfloat16* ap = &in[16*s + j0][kb];
    bf16x8 a0 = *(const bf16x8*)(const void*)(ap);
    bf16x8 a1 = *(const bf16x8*)(const void*)(ap + 32);
    bf16x8 a2 = *(const bf16x8*)(const void*)(ap + 64);
    acc[s] = (f32x4){bv, bv, bv, bv};
    acc[s] = __builtin_amdgcn_mfma_f32_16x16x32_bf16(a0, b0, acc[s], 0, 0, 0);
    acc[s] = __builtin_amdgcn_mfma_f32_16x16x32_bf16(a1, b1, acc[s], 0, 0, 0);
    acc[s] = __builtin_amdgcn_mfma_f32_16x16x32_bf16(a2, b2, acc[s], 0, 0, 0);
  }
}

__device__ __forceinline__ void res2(f32x4 cur[2],
    __hip_bfloat16 (*bA)[LDP], __hip_bfloat16 (*bB)[LDP],
    int j0, int kb, int g, int nt,
    const __hip_bfloat16* __restrict__ w1, const float* __restrict__ b1,
    const __hip_bfloat16* __restrict__ w2, const float* __restrict__ b2)
{
  f32x4 acc[2];
  const int col = 16*nt + j0;
  mfma_layer2(acc, bA, j0, kb, nt, w1, b1);
  #pragma unroll
  for (int s = 0; s < 2; s++){
    int r0 = 16*s + g*4;
    #pragma unroll
    for (int i = 0; i < 4; i++) bB[r0 + i][col] = tob(sp_f(acc[s][i]));
  }
  __syncthreads();
  mfma_layer2(acc, bB, j0, kb, nt, w2, b2);
  #pragma unroll
  for (int s = 0; s < 2; s++){
    int r0 = 16*s + g*4;
    #pragma unroll
    for (int i = 0; i < 4; i++){
      cur[s][i] = sp_f(acc[s][i] + cur[s][i]);
      bA[r0 + i][col] = tob(cur[s][i]);
    }
  }
  __syncthreads();
}

// ---------------------------------------------------------------------------
// Atom kernel: 32 atoms/block, 5 waves (one 16-col block each, 2 row strips)
// grid = N/32 = 512 blocks -> 2 blocks/CU
// ---------------------------------------------------------------------------
__global__ __launch_bounds__(320) void atom_mfma(
    const int*   __restrict__ species,
    const float* __restrict__ features,
    const float* __restrict__ S,
    const __hip_bfloat16* __restrict__ wt,
    const float* __restrict__ bJ, const float* __restrict__ bI,
    const float* __restrict__ ib1, const float* __restrict__ ib2,
    const float* __restrict__ gate, const float* __restrict__ bint,
    const float* __restrict__ ab1, const float* __restrict__ ab2,
    const float* __restrict__ ob1, const float* __restrict__ ob2,
    const float* __restrict__ Wout, const float* __restrict__ bout,
    float* __restrict__ out_e, float* __restrict__ out_f)
{
  __shared__ __align__(16) __hip_bfloat16 bufA[AROWS][LDP];
  __shared__ __align__(16) __hip_bfloat16 bufB[AROWS][LDP];
  __shared__ __align__(16) __hip_bfloat16 xfb[AROWS][LDP];
  __shared__ float mskl[AROWS];
  __shared__ float evp[5][AROWS];

  const int t    = threadIdx.x;
  const int lane = t & 63;
  const int nt   = t >> 6;          // 0..4 : output column block
  const int base = blockIdx.x * AROWS;

  // stage features: raw bf16 -> xfb, softplus bf16 -> bufA
  for (int i = t; i < AROWS * FDIM; i += 320){
    int row = i / FDIM, col = i - row * FDIM;
    float v = features[(size_t)(base + row) * FDIM + col];
    xfb [row][col] = tob(v);
    bufA[row][col] = tob(sp_f(v));
  }
  // zero K-pad cols [80,96) in all three tiles
  for (int i = t; i < 3 * AROWS * 16; i += 320){
    int b = i / (AROWS * 16), rem = i % (AROWS * 16);
    int row = rem >> 4, col = FDIM + (rem & 15);
    if      (b == 0) bufA[row][col] = tob(0.f);
    else if (b == 1) bufB[row][col] = tob(0.f);
    else             xfb [row][col] = tob(0.f);
  }
  if (t < AROWS) mskl[t] = (species[base + t] != -1) ? 1.f : 0.f;
  __syncthreads();

  const int j0  = lane & 15;
  const int g   = lane >> 4;
  const int kb  = g * 8;
  const int col = 16*nt + j0;

  f32x4 cur[2];

  // proto = sp(sp(f)@WJ+bJ) * S + (f@WI+bI)*mask
  {
    f32x4 accJ[2], accI[2];
    mfma_layer2(accJ, bufA, j0, kb, nt, wt + (size_t)0*FDIM*WROW, bJ);
    mfma_layer2(accI, xfb , j0, kb, nt, wt + (size_t)1*FDIM*WROW, bI);
    __syncthreads();   // bufA reads done before overwrite
    #pragma unroll
    for (int s = 0; s < 2; s++){
      int r0 = 16*s + g*4;
      #pragma unroll
      for (int i = 0; i < 4; i++){
        float Sv = S[(size_t)(base + r0 + i) * FDIM + col];
        float m  = mskl[r0 + i];
        cur[s][i] = sp_f(accJ[s][i]) * Sv + accI[s][i] * m;
        bufA[r0 + i][col] = tob(cur[s][i]);
      }
    }
  }
  __syncthreads();

  // message = res_stack(proto, iW)
  #pragma unroll 1
  for (int ir = 0; ir < 3; ir++)
    res2(cur, bufA, bufB, j0, kb, g, nt,
         wt + (size_t)(3+2*ir)*FDIM*WROW, ib1 + ir*FDIM,
         wt + (size_t)(4+2*ir)*FDIM*WROW, ib2 + ir*FDIM);

  // nd = f*gate + sp(message)@Wint + bint
  {
    #pragma unroll
    for (int s = 0; s < 2; s++){
      int r0 = 16*s + g*4;
      #pragma unroll
      for (int i = 0; i < 4; i++) bufB[r0 + i][col] = tob(sp_f(cur[s][i]));
    }
    __syncthreads();
    f32x4 acc[2];
    mfma_layer2(acc, bufB, j0, kb, nt, wt + (size_t)2*FDIM*WROW, bint);
    float gj = gate[col];
    #pragma unroll
    for (int s = 0; s < 2; s++){
      int r0 = 16*s + g*4;
      #pragma unroll
      for (int i = 0; i < 4; i++){
        float xv = __bfloat162float(xfb[r0 + i][col]);
        cur[s][i] = xv * gj + acc[s][i];
        bufA[r0 + i][col] = tob(cur[s][i]);
      }
    }
    __syncthreads();
  }

  // nd = res_stack(nd, aW)
  #pragma unroll 1
  for (int ir = 0; ir < 3; ir++)
    res2(cur, bufA, bufB, j0, kb, g, nt,
         wt + (size_t)(9+2*ir)*FDIM*WROW, ab1 + ir*FDIM,
         wt + (size_t)(10+2*ir)*FDIM*WROW, ab2 + ir*FDIM);

  // out_features = nd * mask
  #pragma unroll
  for (int s = 0; s < 2; s++){
    int r0 = 16*s + g*4;
    #pragma unroll
    for (int i = 0; i < 4; i++)
      out_f[(size_t)(base + r0 + i) * FDIM + col] = cur[s][i] * mskl[r0 + i];
  }

  // t3 = res_stack(nd, oW)
  #pragma unroll 1
  for (int ir = 0; ir < 3; ir++)
    res2(cur, bufA, bufB, j0, kb, g, nt,
         wt + (size_t)(15+2*ir)*FDIM*WROW, ob1 + ir*FDIM,
         wt + (size_t)(16+2*ir)*FDIM*WROW, ob2 + ir*FDIM);

  // energies = (sp(t3) @ Wout + bout) * mask
  {
    float wv = Wout[col];
    float ev[2][4];
    #pragma unroll
    for (int s = 0; s < 2; s++)
      #pragma unroll
      for (int i = 0; i < 4; i++) ev[s][i] = sp_f(cur[s][i]) * wv;
    #pragma unroll
    for (int off = 1; off < 16; off <<= 1){
      #pragma unroll
      for (int s = 0; s < 2; s++)
        #pragma unroll
        for (int i = 0; i < 4; i++) ev[s][i] += __shfl_xor(ev[s][i], off);
    }
    if (j0 == 0){
      #pragma unroll
      for (int s = 0; s < 2; s++)
        #pragma unroll
        for (int i = 0; i < 4; i++) evp[nt][16*s + g*4 + i] = ev[s][i];
    }
  }
  __syncthreads();
  if (t < AROWS)
    out_e[base + t] = (evp[0][t] + evp[1][t] + evp[2][t] + evp[3][t] + evp[4][t]
                       + bout[0]) * mskl[t];
}

// ---------------------------------------------------------------------------
extern "C" void kernel_launch(void* const* d_in, const int* in_sizes, int n_in,
                              void* d_out, int out_size, void* d_ws, size_t ws_size,
                              hipStream_t stream) {
  const int*   species  = (const int*)  d_in[0];
  const float* features = (const float*)d_in[1];
  const float* aev      = (const float*)d_in[2];
  const int*   idx12    = (const int*)  d_in[3];
  const float* WI   = (const float*)d_in[4];  const float* bI   = (const float*)d_in[5];
  const float* Wg   = (const float*)d_in[6];  const float* bg   = (const float*)d_in[7];
  const float* WJ   = (const float*)d_in[8];  const float* bJ   = (const float*)d_in[9];
  const float* iW1  = (const float*)d_in[10]; const float* ib1  = (const float*)d_in[11];
  const float* iW2  = (const float*)d_in[12]; const float* ib2  = (const float*)d_in[13];
  const float* gate = (const float*)d_in[14];
  const float* Wint = (const float*)d_in[15]; const float* bint = (const float*)d_in[16];
  const float* aW1  = (const float*)d_in[17]; const float* ab1  = (const float*)d_in[18];
  const float* aW2  = (const float*)d_in[19]; const float* ab2  = (const float*)d_in[20];
  const float* oW1  = (const float*)d_in[21]; const float* ob1  = (const float*)d_in[22];
  const float* oW2  = (const float*)d_in[23]; const float* ob2  = (const float*)d_in[24];
  const float* Wout = (const float*)d_in[25]; const float* bout = (const float*)d_in[26];

  const int N = in_sizes[1] / FDIM;   // 16384
  const int P = in_sizes[2] / RDIM;   // 393216

  unsigned long long* R6u = (unsigned long long*)d_ws;           // N*6 u64
  float* S = (float*)(R6u + (size_t)N * NSLOT);                  // N*80 f32
  __hip_bfloat16* wt = (__hip_bfloat16*)(S + (size_t)N * FDIM);  // 21*80*96 bf16

  float* out_e = (float*)d_out;
  float* out_f = out_e + N;

  hipMemsetAsync(R6u, 0, (size_t)N * NSLOT * sizeof(unsigned long long), stream);

  WPtrs wp;
  wp.p[0] = WJ; wp.p[1] = WI; wp.p[2] = Wint;
  for (int ir = 0; ir < 3; ir++){
    wp.p[3  + 2*ir] = iW1 + ir*FDIM*FDIM; wp.p[4  + 2*ir] = iW2 + ir*FDIM*FDIM;
    wp.p[9  + 2*ir] = aW1 + ir*FDIM*FDIM; wp.p[10 + 2*ir] = aW2 + ir*FDIM*FDIM;
    wp.p[15 + 2*ir] = oW1 + ir*FDIM*FDIM; wp.p[16 + 2*ir] = oW2 + ir*FDIM*FDIM;
  }
  prep_weights<<<21, 256, 0, stream>>>(wp, wt);

  scatter_p16<<<((size_t)P * NSLOT + 255) / 256, 256, 0, stream>>>(aev, idx12, R6u, P);
  aevt_kernel<<<(N + 63) / 64, TPB2, 0, stream>>>(R6u, Wg, bg, S, N);

  atom_mfma<<<(N + AROWS - 1) / AROWS, 320, 0, stream>>>(species, features, S, wt,
      bJ, bI, ib1, ib2, gate, bint, ab1, ab2, ob1, ob2, Wout, bout, out_e, out_f);
}

// Round 8
// 107.015 us; speedup vs baseline: 1.9171x; 1.0703x over previous
//
#include <hip/hip_runtime.h>
#include <hip/hip_bf16.h>

#define FDIM 80
#define RDIM 20
#define NSLOT 6      // u64 slots per atom row: 24 x 16-bit fields (20 aev + deg + 3 pad)
#define LDP  104     // LDS row stride (bf16)
#define WROW 96      // Wt row stride (bf16), K padded to 96
#define AROWS 32     // atoms per block in atom_mfma

#define FIX_SCALE 512.0f        // 2^9
#define FIX_INV   0.001953125f  // 2^-9

typedef float  f32x4  __attribute__((ext_vector_type(4)));
typedef short  bf16x8 __attribute__((ext_vector_type(8)));

__device__ __forceinline__ float sp_f(float x){
  float e = __expf(-fabsf(x));
  return fmaxf(x, 0.f) + __logf(1.f + e);
}
__device__ __forceinline__ __hip_bfloat16 tob(float x){ return __float2bfloat16(x); }

// ---------------------------------------------------------------------------
// Weight prep: Wt[slot][j][k] = bf16(W[k][j]), zero-padded k in [80,96)
// ---------------------------------------------------------------------------
struct WPtrs { const float* p[21]; };

__global__ __launch_bounds__(256) void prep_weights(WPtrs wp, __hip_bfloat16* __restrict__ wt){
  const float* W = wp.p[blockIdx.x];
  __hip_bfloat16* dst = wt + (size_t)blockIdx.x * FDIM * WROW;
  for (int i = threadIdx.x; i < FDIM * WROW; i += 256){
    int j = i / WROW, k = i - j * WROW;
    dst[i] = __float2bfloat16(k < FDIM ? W[k * FDIM + j] : 0.f);
  }
}

// ---------------------------------------------------------------------------
// Scatter, 16-bit fixed-point, 4 fields per u64 (at atomic-payload floor)
// ---------------------------------------------------------------------------
__global__ __launch_bounds__(256) void scatter_p16(const float* __restrict__ aev,
    const int* __restrict__ idx12, unsigned long long* __restrict__ R6u, int P)
{
  int g = blockIdx.x * 256 + threadIdx.x;
  if (g >= P * NSLOT) return;
  int p = g / NSLOT, s = g - p * NSLOT;
  unsigned long long v;
  if (s < 5){
    float4 a = ((const float4*)(aev + (size_t)p * RDIM))[s];
    unsigned long long f0 = (unsigned long long)__float2uint_rn(a.x * FIX_SCALE);
    unsigned long long f1 = (unsigned long long)__float2uint_rn(a.y * FIX_SCALE);
    unsigned long long f2 = (unsigned long long)__float2uint_rn(a.z * FIX_SCALE);
    unsigned long long f3 = (unsigned long long)__float2uint_rn(a.w * FIX_SCALE);
    v = f0 | (f1 << 16) | (f2 << 32) | (f3 << 48);
  } else {
    v = 512ULL;   // deg increment (unpacks to 1.0)
  }
  int i1 = idx12[p], i2 = idx12[P + p];
  atomicAdd(&R6u[(size_t)i1 * NSLOT + s], v);
  atomicAdd(&R6u[(size_t)i2 * NSLOT + s], v);
}

// ---------------------------------------------------------------------------
// Weight fragment (one layer's B-operand for this thread) + rolling prefetch
// ---------------------------------------------------------------------------
struct WF { bf16x8 b0, b1, b2; float bias; };

__device__ __forceinline__ WF loadWF(const __hip_bfloat16* __restrict__ wb,
                                     int slot, const float* __restrict__ bias, int row){
  WF w;
  const __hip_bfloat16* p = wb + (size_t)slot * (FDIM * WROW);
  w.b0 = *(const bf16x8*)(const void*)(p);
  w.b1 = *(const bf16x8*)(const void*)(p + 32);
  w.b2 = *(const bf16x8*)(const void*)(p + 64);
  w.bias = bias[row];
  return w;
}

// A-frag: m=lane&15, k=(lane>>4)*8+e (+32ks). C/D: col=lane&15, row=(lane>>4)*4+i.
__device__ __forceinline__ void mfmaL(f32x4 acc[2],
    const __hip_bfloat16 (*in)[LDP], int j0, int kb, const WF& w)
{
  #pragma unroll
  for (int s = 0; s < 2; s++){
    const __hip_bfloat16* ap = &in[16*s + j0][kb];
    bf16x8 a0 = *(const bf16x8*)(const void*)(ap);
    bf16x8 a1 = *(const bf16x8*)(const void*)(ap + 32);
    bf16x8 a2 = *(const bf16x8*)(const void*)(ap + 64);
    acc[s] = (f32x4){w.bias, w.bias, w.bias, w.bias};
    acc[s] = __builtin_amdgcn_mfma_f32_16x16x32_bf16(a0, w.b0, acc[s], 0, 0, 0);
    acc[s] = __builtin_amdgcn_mfma_f32_16x16x32_bf16(a1, w.b1, acc[s], 0, 0, 0);
    acc[s] = __builtin_amdgcn_mfma_f32_16x16x32_bf16(a2, w.b2, acc[s], 0, 0, 0);
  }
}

// One residual block: uses preloaded w1,w2; prefetches pf1->w1, pf2->w2.
__device__ __forceinline__ void resblk(f32x4 cur[2],
    __hip_bfloat16 (*bA)[LDP], __hip_bfloat16 (*bB)[LDP],
    int j0, int kb, int g, int col,
    WF& w1, WF& w2,
    const __hip_bfloat16* __restrict__ wb, int row,
    int pf1, const float* __restrict__ pf1b,
    int pf2, const float* __restrict__ pf2b)
{
  f32x4 acc[2];
  mfmaL(acc, bA, j0, kb, w1);
  w1 = loadWF(wb, pf1, pf1b, row);
  #pragma unroll
  for (int s = 0; s < 2; s++){
    int r0 = 16*s + g*4;
    #pragma unroll
    for (int i = 0; i < 4; i++) bB[r0 + i][col] = tob(sp_f(acc[s][i]));
  }
  __syncthreads();
  mfmaL(acc, bB, j0, kb, w2);
  w2 = loadWF(wb, pf2, pf2b, row);
  #pragma unroll
  for (int s = 0; s < 2; s++){
    int r0 = 16*s + g*4;
    #pragma unroll
    for (int i = 0; i < 4; i++){
      cur[s][i] = sp_f(acc[s][i] + cur[s][i]);
      bA[r0 + i][col] = tob(cur[s][i]);
    }
  }
  __syncthreads();
}

// ---------------------------------------------------------------------------
// Atom kernel: 32 atoms/block, 5 waves; S computed in-kernel from R6u;
// rolling weight prefetch across all 21 layers.
// ---------------------------------------------------------------------------
__global__ __launch_bounds__(320, 4) void atom_mfma(
    const int*   __restrict__ species,
    const float* __restrict__ features,
    const unsigned long long* __restrict__ R6u,
    const __hip_bfloat16* __restrict__ wt,
    const float* __restrict__ Wg, const float* __restrict__ bg,
    const float* __restrict__ bJ, const float* __restrict__ bI,
    const float* __restrict__ ib1, const float* __restrict__ ib2,
    const float* __restrict__ gate, const float* __restrict__ bint,
    const float* __restrict__ ab1, const float* __restrict__ ab2,
    const float* __restrict__ ob1, const float* __restrict__ ob2,
    const float* __restrict__ Wout, const float* __restrict__ bout,
    float* __restrict__ out_e, float* __restrict__ out_f)
{
  __shared__ __align__(16) __hip_bfloat16 bufA[AROWS][LDP];
  __shared__ __align__(16) __hip_bfloat16 bufB[AROWS][LDP];
  __shared__ __align__(16) __hip_bfloat16 xfb[AROWS][LDP];
  __shared__ float Rl[AROWS][4 * NSLOT];
  __shared__ float mskl[AROWS];
  __shared__ float evp[5][AROWS];

  const int t    = threadIdx.x;
  const int lane = t & 63;
  const int nt   = t >> 6;          // 0..4 : output column block
  const int base = blockIdx.x * AROWS;

  const int j0  = lane & 15;
  const int g   = lane >> 4;
  const int kb  = g * 8;
  const int col = 16*nt + j0;
  const int row = col;                       // B-frag row == output col
  const __hip_bfloat16* wb = wt + (size_t)row * WROW + kb;

  // early: Wg column for in-kernel S computation (dead after Sreg)
  float wgc[RDIM];
  #pragma unroll
  for (int r = 0; r < RDIM; r++) wgc[r] = Wg[r * FDIM + col];
  const float bgv = bg[col];

  // stage features: raw bf16 -> xfb, softplus bf16 -> bufA
  for (int i = t; i < AROWS * FDIM; i += 320){
    int rr = i / FDIM, cc = i - rr * FDIM;
    float v = features[(size_t)(base + rr) * FDIM + cc];
    xfb [rr][cc] = tob(v);
    bufA[rr][cc] = tob(sp_f(v));
  }
  // zero K-pad cols [80,96)
  for (int i = t; i < 3 * AROWS * 16; i += 320){
    int b = i / (AROWS * 16), rem = i % (AROWS * 16);
    int rr = rem >> 4, cc = FDIM + (rem & 15);
    if      (b == 0) bufA[rr][cc] = tob(0.f);
    else if (b == 1) bufB[rr][cc] = tob(0.f);
    else             xfb [rr][cc] = tob(0.f);
  }
  // stage + unpack R
  if (t < AROWS * NSLOT){
    int u = t / NSLOT, s5 = t - u * NSLOT;
    unsigned long long v = R6u[(size_t)(base + u) * NSLOT + s5];
    #pragma unroll
    for (int f = 0; f < 4; f++)
      Rl[u][4*s5 + f] = (float)((unsigned int)(v >> (16*f)) & 0xffffu) * FIX_INV;
  }
  if (t < AROWS) mskl[t] = (species[base + t] != -1) ? 1.f : 0.f;
  __syncthreads();

  // S in registers: Sreg[s][i] for rows 16s+g*4+i, column `col`
  f32x4 Sreg[2];
  #pragma unroll
  for (int s = 0; s < 2; s++){
    #pragma unroll
    for (int i = 0; i < 4; i++){
      int rr = 16*s + g*4 + i;
      float a = Rl[rr][RDIM] * bgv;
      #pragma unroll
      for (int r = 0; r < RDIM; r++) a += Rl[rr][r] * wgc[r];
      Sreg[s][i] = a;
    }
  }

  f32x4 cur[2];

  // proto = sp(sp(f)@WJ+bJ) * S + (f@WI+bI)*mask   (layers L0,L1)
  {
    WF wA = loadWF(wb, 0, bJ, row);
    WF wB = loadWF(wb, 1, bI, row);
    f32x4 aJ[2], aI[2];
    mfmaL(aJ, bufA, j0, kb, wA);  wA = loadWF(wb, 3, ib1, row);
    mfmaL(aI, xfb , j0, kb, wB);  wB = loadWF(wb, 4, ib2, row);
    __syncthreads();   // bufA reads done before overwrite
    #pragma unroll
    for (int s = 0; s < 2; s++){
      int r0 = 16*s + g*4;
      #pragma unroll
      for (int i = 0; i < 4; i++){
        cur[s][i] = sp_f(aJ[s][i]) * Sreg[s][i] + aI[s][i] * mskl[r0 + i];
        bufA[r0 + i][col] = tob(cur[s][i]);
      }
    }
    __syncthreads();

    // message = res_stack(proto, iW): slots (3,4),(5,6),(7,8)
    resblk(cur, bufA, bufB, j0, kb, g, col, wA, wB, wb, row,
           5, ib1 + FDIM,     6, ib2 + FDIM);
    resblk(cur, bufA, bufB, j0, kb, g, col, wA, wB, wb, row,
           7, ib1 + 2*FDIM,   8, ib2 + 2*FDIM);
    resblk(cur, bufA, bufB, j0, kb, g, col, wA, wB, wb, row,
           2, bint,           9, ab1);

    // nd = f*gate + sp(message)@Wint + bint   (layer L8, uses wA=slot2)
    #pragma unroll
    for (int s = 0; s < 2; s++){
      int r0 = 16*s + g*4;
      #pragma unroll
      for (int i = 0; i < 4; i++) bufB[r0 + i][col] = tob(sp_f(cur[s][i]));
    }
    __syncthreads();
    {
      f32x4 acc[2];
      mfmaL(acc, bufB, j0, kb, wA);
      wA = loadWF(wb, 10, ab2, row);
      float gj = gate[col];
      #pragma unroll
      for (int s = 0; s < 2; s++){
        int r0 = 16*s + g*4;
        #pragma unroll
        for (int i = 0; i < 4; i++){
          float xv = __bfloat162float(xfb[r0 + i][col]);
          cur[s][i] = xv * gj + acc[s][i];
          bufA[r0 + i][col] = tob(cur[s][i]);
        }
      }
    }
    __syncthreads();

    // nd = res_stack(nd, aW): slots (9,10),(11,12),(13,14)  [w1=wB, w2=wA]
    resblk(cur, bufA, bufB, j0, kb, g, col, wB, wA, wb, row,
           11, ab1 + FDIM,    12, ab2 + FDIM);
    resblk(cur, bufA, bufB, j0, kb, g, col, wB, wA, wb, row,
           13, ab1 + 2*FDIM,  14, ab2 + 2*FDIM);
    resblk(cur, bufA, bufB, j0, kb, g, col, wB, wA, wb, row,
           15, ob1,           16, ob2);

    // out_features = nd * mask
    #pragma unroll
    for (int s = 0; s < 2; s++){
      int r0 = 16*s + g*4;
      #pragma unroll
      for (int i = 0; i < 4; i++)
        out_f[(size_t)(base + r0 + i) * FDIM + col] = cur[s][i] * mskl[r0 + i];
    }

    // t3 = res_stack(nd, oW): slots (15,16),(17,18),(19,20)
    resblk(cur, bufA, bufB, j0, kb, g, col, wB, wA, wb, row,
           17, ob1 + FDIM,    18, ob2 + FDIM);
    resblk(cur, bufA, bufB, j0, kb, g, col, wB, wA, wb, row,
           19, ob1 + 2*FDIM,  20, ob2 + 2*FDIM);
    resblk(cur, bufA, bufB, j0, kb, g, col, wB, wA, wb, row,
           0, bJ,             0, bJ);   // dummy prefetch
  }

  // energies = (sp(t3) @ Wout + bout) * mask
  {
    float wv = Wout[col];
    float ev[2][4];
    #pragma unroll
    for (int s = 0; s < 2; s++)
      #pragma unroll
      for (int i = 0; i < 4; i++) ev[s][i] = sp_f(cur[s][i]) * wv;
    #pragma unroll
    for (int off = 1; off < 16; off <<= 1){
      #pragma unroll
      for (int s = 0; s < 2; s++)
        #pragma unroll
        for (int i = 0; i < 4; i++) ev[s][i] += __shfl_xor(ev[s][i], off);
    }
    if (j0 == 0){
      #pragma unroll
      for (int s = 0; s < 2; s++)
        #pragma unroll
        for (int i = 0; i < 4; i++) evp[nt][16*s + g*4 + i] = ev[s][i];
    }
  }
  __syncthreads();
  if (t < AROWS)
    out_e[base + t] = (evp[0][t] + evp[1][t] + evp[2][t] + evp[3][t] + evp[4][t]
                       + bout[0]) * mskl[t];
}

// ---------------------------------------------------------------------------
extern "C" void kernel_launch(void* const* d_in, const int* in_sizes, int n_in,
                              void* d_out, int out_size, void* d_ws, size_t ws_size,
                              hipStream_t stream) {
  const int*   species  = (const int*)  d_in[0];
  const float* features = (const float*)d_in[1];
  const float* aev      = (const float*)d_in[2];
  const int*   idx12    = (const int*)  d_in[3];
  const float* WI   = (const float*)d_in[4];  const float* bI   = (const float*)d_in[5];
  const float* Wg   = (const float*)d_in[6];  const float* bg   = (const float*)d_in[7];
  const float* WJ   = (const float*)d_in[8];  const float* bJ   = (const float*)d_in[9];
  const float* iW1  = (const float*)d_in[10]; const float* ib1  = (const float*)d_in[11];
  const float* iW2  = (const float*)d_in[12]; const float* ib2  = (const float*)d_in[13];
  const float* gate = (const float*)d_in[14];
  const float* Wint = (const float*)d_in[15]; const float* bint = (const float*)d_in[16];
  const float* aW1  = (const float*)d_in[17]; const float* ab1  = (const float*)d_in[18];
  const float* aW2  = (const float*)d_in[19]; const float* ab2  = (const float*)d_in[20];
  const float* oW1  = (const float*)d_in[21]; const float* ob1  = (const float*)d_in[22];
  const float* oW2  = (const float*)d_in[23]; const float* ob2  = (const float*)d_in[24];
  const float* Wout = (const float*)d_in[25]; const float* bout = (const float*)d_in[26];

  const int N = in_sizes[1] / FDIM;   // 16384
  const int P = in_sizes[2] / RDIM;   // 393216

  unsigned long long* R6u = (unsigned long long*)d_ws;           // N*6 u64
  __hip_bfloat16* wt = (__hip_bfloat16*)(R6u + (size_t)N * NSLOT);  // 21*80*96 bf16

  float* out_e = (float*)d_out;
  float* out_f = out_e + N;

  hipMemsetAsync(R6u, 0, (size_t)N * NSLOT * sizeof(unsigned long long), stream);

  WPtrs wp;
  wp.p[0] = WJ; wp.p[1] = WI; wp.p[2] = Wint;
  for (int ir = 0; ir < 3; ir++){
    wp.p[3  + 2*ir] = iW1 + ir*FDIM*FDIM; wp.p[4  + 2*ir] = iW2 + ir*FDIM*FDIM;
    wp.p[9  + 2*ir] = aW1 + ir*FDIM*FDIM; wp.p[10 + 2*ir] = aW2 + ir*FDIM*FDIM;
    wp.p[15 + 2*ir] = oW1 + ir*FDIM*FDIM; wp.p[16 + 2*ir] = oW2 + ir*FDIM*FDIM;
  }
  prep_weights<<<21, 256, 0, stream>>>(wp, wt);

  scatter_p16<<<((size_t)P * NSLOT + 255) / 256, 256, 0, stream>>>(aev, idx12, R6u, P);

  atom_mfma<<<(N + AROWS - 1) / AROWS, 320, 0, stream>>>(species, features, R6u, wt,
      Wg, bg, bJ, bI, ib1, ib2, gate, bint, ab1, ab2, ob1, ob2, Wout, bout,
      out_e, out_f);
}